// Round 3
// baseline (226.005 us; speedup 1.0000x reference)
//
#include <hip/hip_runtime.h>
#include <hip/hip_bf16.h>
#include <cstdint>
#include <math.h>

#define B_    2
#define S_    2048
#define DIM_  1536
#define H_    12
#define HD_   128
#define TRI_  4608   // 3*DIM
#define M_    4096   // B*S

typedef __attribute__((ext_vector_type(8)))  __bf16 bf16x8;
typedef __attribute__((ext_vector_type(4)))  __bf16 bf16x4;
typedef __attribute__((ext_vector_type(4)))  float  floatx4;
typedef __attribute__((ext_vector_type(16))) float  floatx16;

typedef __attribute__((address_space(3))) uint8_t       lds_u8;
typedef const __attribute__((address_space(1))) uint8_t glob_u8;

// ---------------- prep: W1/W2 transpose+cvt, x cvt — one launch
__global__ __launch_bounds__(256) void prep(const float* __restrict__ W1,
                                            __bf16* __restrict__ O1,
                                            const float* __restrict__ W2,
                                            __bf16* __restrict__ O2,
                                            const float* __restrict__ x,
                                            __bf16* __restrict__ x_bf) {
    const int T1 = (TRI_ / 64) * (DIM_ / 64);   // 1728
    const int T2 = (DIM_ / 64) * (DIM_ / 64);   // 576
    int blk = blockIdx.x;
    const int t = threadIdx.x;

    if (blk >= T1 + T2) {                       // cvt x -> bf16
        blk -= T1 + T2;
        int i = blk * 256 + t;
        float4 v = ((const float4*)x)[i];
        bf16x4 o;
        o.x = (__bf16)v.x; o.y = (__bf16)v.y; o.z = (__bf16)v.z; o.w = (__bf16)v.w;
        *(bf16x4*)(x_bf + (size_t)i * 4) = o;
        return;
    }

    const float* in; __bf16* out; int R, C, c0, r0;
    if (blk < T1) {
        in = W1; out = O1; R = DIM_; C = TRI_;
        c0 = (blk % (TRI_ / 64)) * 64; r0 = (blk / (TRI_ / 64)) * 64;
    } else {
        blk -= T1;
        in = W2; out = O2; R = DIM_; C = DIM_;
        c0 = (blk % (DIM_ / 64)) * 64; r0 = (blk / (DIM_ / 64)) * 64;
    }
    __shared__ float tile[64][65];
    const int c4 = t & 15, r = t >> 4;
    #pragma unroll
    for (int i = 0; i < 64; i += 16) {
        float4 v = *(const float4*)&in[(size_t)(r0 + r + i) * C + c0 + c4 * 4];
        tile[r + i][c4 * 4 + 0] = v.x;
        tile[r + i][c4 * 4 + 1] = v.y;
        tile[r + i][c4 * 4 + 2] = v.z;
        tile[r + i][c4 * 4 + 3] = v.w;
    }
    __syncthreads();
    const int cc = t >> 2, ch = t & 3;
    #pragma unroll
    for (int cho = 0; cho < 8; cho += 4) {
        int chh = ch + cho;
        bf16x8 o;
        #pragma unroll
        for (int k = 0; k < 8; ++k) o[k] = (__bf16)tile[chh * 8 + k][cc];
        *(bf16x8*)&out[(size_t)(c0 + cc) * R + r0 + chh * 8] = o;
    }
}

// -------------------- QKV GEMM 128x192, BK=64, DOUBLE-buffer 2-phase
// stage(t+1) issued before compute(t); ONE __syncthreads per K-step (drain
// lands after MFMA of previous step). LDS 80 KB -> 2 blocks/CU.
__global__ __launch_bounds__(256, 2) void gemm_qkv(const __bf16* __restrict__ A,
                                                   const __bf16* __restrict__ Bt,
                                                   const float*  __restrict__ bias,
                                                   __bf16* __restrict__ Cout,
                                                   int Mdim, int Ndim, int Kdim) {
    __shared__ __align__(16) __bf16 sA[2][128 * 64];   // 32 KB
    __shared__ __align__(16) __bf16 sB[2][192 * 64];   // 48 KB

    const int ntiles = Ndim / 192;
    const int tile_n = blockIdx.x % ntiles;
    const int tile_m = blockIdx.x / ntiles;
    const int m0 = tile_m << 7, n0 = tile_n * 192;

    const int tid  = threadIdx.x;
    const int lane = tid & 63;
    const int wave = tid >> 6;
    const int wm = (wave >> 1) * 64;
    const int wn = (wave & 1) * 96;

    floatx16 acc[2][3] = {};

    const int lr8 = lane >> 3;                  // staging row within 8-row group
    const int swz = (((lane & 7) ^ lr8) * 8);   // staging source chunk (swizzled)

    const int m32  = lane & 31;                 // MFMA row/col within 32
    const int half = lane >> 5;                 // k-half selector
    const int lx7  = lane & 7;                  // row&7 for frag reads

    auto stage = [&](int buf, int kk) {
        #pragma unroll
        for (int c = 0; c < 4; ++c) {
            int r0 = wave * 32 + c * 8;
            const __bf16* ga = A + (size_t)(m0 + r0 + lr8) * Kdim + kk + swz;
            __builtin_amdgcn_global_load_lds((glob_u8*)ga, (lds_u8*)&sA[buf][r0 * 64], 16, 0, 0);
        }
        #pragma unroll
        for (int c = 0; c < 6; ++c) {
            int r0 = wave * 48 + c * 8;
            const __bf16* gb = Bt + (size_t)(n0 + r0 + lr8) * Kdim + kk + swz;
            __builtin_amdgcn_global_load_lds((glob_u8*)gb, (lds_u8*)&sB[buf][r0 * 64], 16, 0, 0);
        }
    };

    stage(0, 0);
    for (int k0 = 0; k0 < Kdim; k0 += 64) {
        const int cur = (k0 >> 6) & 1;
        __syncthreads();                        // drains stage(cur); after prev MFMAs
        if (k0 + 64 < Kdim) stage(cur ^ 1, k0 + 64);

        #pragma unroll
        for (int ks = 0; ks < 4; ++ks) {        // 4 k-steps of 16
            const int ko = (((ks * 2 + half) ^ lx7) * 8);
            bf16x8 af[2], bfr[3];
            #pragma unroll
            for (int i = 0; i < 2; ++i)
                af[i] = *(const bf16x8*)&sA[cur][(wm + i * 32 + m32) * 64 + ko];
            #pragma unroll
            for (int j = 0; j < 3; ++j)
                bfr[j] = *(const bf16x8*)&sB[cur][(wn + j * 32 + m32) * 64 + ko];
            #pragma unroll
            for (int i = 0; i < 2; ++i)
                #pragma unroll
                for (int j = 0; j < 3; ++j)
                    acc[i][j] = __builtin_amdgcn_mfma_f32_32x32x16_bf16(af[i], bfr[j], acc[i][j], 0, 0, 0);
        }
    }

    // C/D layout (m74/m101): col = lane&31, row = (reg&3) + 8*(reg>>2) + 4*(lane>>5)
    #pragma unroll
    for (int j = 0; j < 3; ++j) {
        int gc = n0 + wn + j * 32 + m32;
        float bv = bias[gc];
        #pragma unroll
        for (int i = 0; i < 2; ++i) {
            #pragma unroll
            for (int r = 0; r < 16; ++r) {
                int gr = m0 + wm + i * 32 + (r & 3) + 8 * (r >> 2) + 4 * half;
                Cout[(size_t)gr * Ndim + gc] = (__bf16)(acc[i][j][r] + bv);
            }
        }
    }
}

// ---------------- out GEMM: 64x128 tile, BK=64, DOUBLE-buffer 2-phase
// LDS 48 KB -> keeps 3 blocks/CU (grid 768 = 3.0/CU balanced) + overlap.
// 4 waves each 32x64 as 2x4 of 16x16 frags; qkv-style 3-bit XOR swizzle.
__global__ __launch_bounds__(256, 3) void gemm_out(const __bf16* __restrict__ A,
                                                   const __bf16* __restrict__ Bt,
                                                   const float*  __restrict__ bias,
                                                   float* __restrict__ Cout,
                                                   int Mdim, int Ndim, int Kdim) {
    __shared__ __align__(16) __bf16 sA[2][64 * 64];    // 16 KB
    __shared__ __align__(16) __bf16 sB[2][128 * 64];   // 32 KB

    const int ntiles = Ndim >> 7;            // 12
    const int tile_n = blockIdx.x % ntiles;
    const int tile_m = blockIdx.x / ntiles;
    const int m0 = tile_m << 6, n0 = tile_n << 7;

    const int tid  = threadIdx.x;
    const int lane = tid & 63;
    const int wave = tid >> 6;
    const int wm = (wave >> 1) * 32;         // 2 wave-rows of 32
    const int wn = (wave & 1) * 64;          // 2 wave-cols of 64

    floatx4 acc[2][4] = {};

    const int lr8 = lane >> 3;
    const int swz = ((lane & 7) ^ lr8) * 8;

    const int row  = lane & 15;
    const int quad = lane >> 4;

    auto stage = [&](int buf, int kk) {
        #pragma unroll
        for (int c = 0; c < 2; ++c) {            // A: 64 rows
            int r0 = wave * 16 + c * 8;
            const __bf16* ga = A + (size_t)(m0 + r0 + lr8) * Kdim + kk + swz;
            __builtin_amdgcn_global_load_lds((glob_u8*)ga, (lds_u8*)&sA[buf][r0 * 64], 16, 0, 0);
        }
        #pragma unroll
        for (int c = 0; c < 4; ++c) {            // B: 128 rows
            int r0 = wave * 32 + c * 8;
            const __bf16* gb = Bt + (size_t)(n0 + r0 + lr8) * Kdim + kk + swz;
            __builtin_amdgcn_global_load_lds((glob_u8*)gb, (lds_u8*)&sB[buf][r0 * 64], 16, 0, 0);
        }
    };

    stage(0, 0);
    for (int k0 = 0; k0 < Kdim; k0 += 64) {
        const int cur = (k0 >> 6) & 1;
        __syncthreads();
        if (k0 + 64 < Kdim) stage(cur ^ 1, k0 + 64);

        #pragma unroll
        for (int ks = 0; ks < 2; ++ks) {
            const int ck = ((ks * 4 + quad) ^ (row & 7)) * 8;
            bf16x8 af[2], bfr[4];
            #pragma unroll
            for (int i = 0; i < 2; ++i)
                af[i]  = *(const bf16x8*)&sA[cur][(wm + i * 16 + row) * 64 + ck];
            #pragma unroll
            for (int j = 0; j < 4; ++j)
                bfr[j] = *(const bf16x8*)&sB[cur][(wn + j * 16 + row) * 64 + ck];
            #pragma unroll
            for (int i = 0; i < 2; ++i)
                #pragma unroll
                for (int j = 0; j < 4; ++j)
                    acc[i][j] = __builtin_amdgcn_mfma_f32_16x16x32_bf16(af[i], bfr[j], acc[i][j], 0, 0, 0);
        }
    }

    #pragma unroll
    for (int j = 0; j < 4; ++j) {
        int gc = n0 + wn + j * 16 + row;
        float bv = bias[gc];
        #pragma unroll
        for (int i = 0; i < 2; ++i) {
            #pragma unroll
            for (int r = 0; r < 4; ++r) {
                int gr = m0 + wm + i * 16 + quad * 4 + r;
                Cout[(size_t)gr * Ndim + gc] = acc[i][j][r] + bv;
            }
        }
    }
}

// ------------------------------------------------------------------ anchor attention
// v2: LDS-tiled. Block = (b, h, 64-query chunk); grid 2*12*32 = 768 blocks, 256 thr.
#define AROWS 86          // 84 halo rows + 2 global rows
#define ATOT  2752        // 2*86*16 chunk-loads of 16B

__global__ __launch_bounds__(256) void anchor_attn(const __bf16* __restrict__ qkv,
                                                   const float* __restrict__ group_scale,
                                                   __bf16* __restrict__ attn_out) {
    const int sc = blockIdx.x;          // 0..31  : 64-query chunk
    const int h  = blockIdx.y;          // 0..11
    const int b  = blockIdx.z;          // 0..1
    const int s0 = sc * 64;

    __shared__ __align__(16) __bf16 sKV[2 * AROWS * 128];   // K then V, 44 KB

    const int tid  = threadIdx.x;
    const int wave = tid >> 6;

    // ---- stage K and V rows (pre-swizzled source, linear LDS dest)
    #pragma unroll
    for (int base = 0; base < ATOT; base += 256) {
        int i = base + tid;
        if (i < ATOT) {
            int r  = i >> 4;                    // 0..171 combined K/V row
            int c  = i & 15;                    // dest 16B chunk
            int kv = (r >= AROWS) ? 1 : 0;
            int rr = r - AROWS * kv;            // 0..85
            int s_row = (rr < 84) ? min(max(s0 - 10 + rr, 0), S_ - 1)
                                  : (rr == 84 ? 0 : S_ - 1);
            int cs = c ^ (rr & 7);              // pre-swizzled source chunk
            const __bf16* src = qkv + (size_t)(b * S_ + s_row) * TRI_
                              + DIM_ * (1 + kv) + h * HD_ + cs * 8;
            __builtin_amdgcn_global_load_lds((glob_u8*)src,
                (lds_u8*)sKV + (size_t)(base + wave * 64) * 16, 16, 0, 0);
        }
    }

    // ---- log group weights (redundant per thread, cheap)
    float g0 = group_scale[0], g1 = group_scale[1], g2 = group_scale[2];
    float gm = fmaxf(g0, fmaxf(g1, g2));
    float e0 = __expf(g0 - gm), e1 = __expf(g1 - gm), e2 = __expf(g2 - gm);
    float ls = __logf(e0 + e1 + e2);
    float lw0 = g0 - gm - ls, lw1 = g1 - gm - ls, lw2 = g2 - gm - ls;

    const int s_local = tid >> 2;       // 0..63
    const int ds      = tid & 3;        // 32-dim slice
    const int s       = s0 + s_local;

    // ---- Q slice -> registers (fp32)
    float q[32];
    {
        const __bf16* qp = qkv + (size_t)(b * S_ + s) * TRI_ + h * HD_ + ds * 32;
        #pragma unroll
        for (int j = 0; j < 4; ++j) {
            bf16x8 qv = *(const bf16x8*)(qp + j * 8);
            #pragma unroll
            for (int k = 0; k < 8; ++k) q[j * 8 + k] = (float)qv[k];
        }
    }

    // anchor LDS slots
    int slot[12];
    const int offs[10] = {-3, -2, -1, 1, 2, 3, -10, -5, 5, 10};
    #pragma unroll
    for (int a = 0; a < 10; ++a) slot[a] = s_local + 10 + offs[a];   // 0..83
    slot[10] = 84; slot[11] = 85;

    __syncthreads();

    const float scale = 0.08838834764831845f;
    float p[12];
    float mx = -1e30f;
    #pragma unroll
    for (int a = 0; a < 12; ++a) {
        const int ro = slot[a] * 128;
        const int sw = slot[a] & 7;
        float d = 0.f;
        #pragma unroll
        for (int j = 0; j < 4; ++j) {
            bf16x8 kv = *(const bf16x8*)&sKV[ro + ((ds * 4 + j) ^ sw) * 8];
            #pragma unroll
            for (int k = 0; k < 8; ++k) d += q[j * 8 + k] * (float)kv[k];
        }
        d += __shfl_xor(d, 1); d += __shfl_xor(d, 2);   // reduce over 4-lane group
        float v = d * scale + (a < 6 ? lw0 : (a < 10 ? lw1 : lw2));
        p[a] = v;
        mx = fmaxf(mx, v);
    }
    float l = 0.f;
    #pragma unroll
    for (int a = 0; a < 12; ++a) { p[a] = __expf(p[a] - mx); l += p[a]; }
    float inv = 1.0f / l;

    float o[32] = {};
    #pragma unroll
    for (int a = 0; a < 12; ++a) {
        const int ro = AROWS * 128 + slot[a] * 128;
        const int sw = slot[a] & 7;
        float pa = p[a];
        #pragma unroll
        for (int j = 0; j < 4; ++j) {
            bf16x8 vv = *(const bf16x8*)&sKV[ro + ((ds * 4 + j) ^ sw) * 8];
            #pragma unroll
            for (int k = 0; k < 8; ++k) o[j * 8 + k] += pa * (float)vv[k];
        }
    }

    __bf16* op = attn_out + (size_t)(b * S_ + s) * DIM_ + h * HD_ + ds * 32;
    #pragma unroll
    for (int j = 0; j < 4; ++j) {
        bf16x8 ov;
        #pragma unroll
        for (int k = 0; k < 8; ++k) ov[k] = (__bf16)(o[j * 8 + k] * inv);
        *(bf16x8*)(op + j * 8) = ov;
    }
}

// ----------------------------------------------------------------------- launcher
extern "C" void kernel_launch(void* const* d_in, const int* in_sizes, int n_in,
                              void* d_out, int out_size, void* d_ws, size_t ws_size,
                              hipStream_t stream) {
    const float* x    = (const float*)d_in[0];
    const float* Wqkv = (const float*)d_in[1];
    const float* bqkv = (const float*)d_in[2];
    const float* Wout = (const float*)d_in[3];
    const float* bout = (const float*)d_in[4];
    const float* gsc  = (const float*)d_in[5];
    float* out = (float*)d_out;

    char* ws = (char*)d_ws;
    __bf16* x_bf   = (__bf16*)(ws);
    __bf16* WqkvT  = (__bf16*)(ws + 12582912);
    __bf16* WoutT  = (__bf16*)(ws + 12582912 + 14155776);
    __bf16* qkv    = (__bf16*)(ws + 12582912 + 14155776 + 4718592);
    __bf16* attn   = (__bf16*)(ws + 12582912 + 14155776 + 4718592 + 37748736);

    // prep: transposes + cvt (one launch)
    {
        int nblk = (TRI_ / 64) * (DIM_ / 64) + (DIM_ / 64) * (DIM_ / 64)
                 + (M_ * DIM_) / 1024;
        prep<<<nblk, 256, 0, stream>>>(Wqkv, WqkvT, Wout, WoutT, x, x_bf);
    }

    // QKV GEMM: 128x192 tiles -> 768 blocks, 2-phase dbuf
    gemm_qkv<<<(M_ / 128) * (TRI_ / 192), 256, 0, stream>>>(
        x_bf, WqkvT, bqkv, qkv, M_, TRI_, DIM_);

    // anchor attention v2: LDS-tiled, grid (32, 12, 2)
    anchor_attn<<<dim3(32, H_, B_), 256, 0, stream>>>(qkv, gsc, attn);

    // out GEMM: 64x128 tiles, BK=64 dbuf 2-phase -> 768 blocks (3.0/CU)
    gemm_out<<<(M_ / 64) * (DIM_ / 128), 256, 0, stream>>>(
        attn, WoutT, bout, out, M_, DIM_, DIM_);
}

// Round 4
// 217.038 us; speedup vs baseline: 1.0413x; 1.0413x over previous
//
#include <hip/hip_runtime.h>
#include <hip/hip_bf16.h>
#include <cstdint>
#include <math.h>

#define B_    2
#define S_    2048
#define DIM_  1536
#define H_    12
#define HD_   128
#define TRI_  4608   // 3*DIM
#define M_    4096   // B*S

typedef __attribute__((ext_vector_type(8)))  __bf16 bf16x8;
typedef __attribute__((ext_vector_type(4)))  __bf16 bf16x4;
typedef __attribute__((ext_vector_type(4)))  float  floatx4;
typedef __attribute__((ext_vector_type(16))) float  floatx16;

typedef __attribute__((address_space(3))) uint8_t       lds_u8;
typedef const __attribute__((address_space(1))) uint8_t glob_u8;

// ---------------- prep: W1/W2 transpose+cvt, x cvt — one launch
__global__ __launch_bounds__(256) void prep(const float* __restrict__ W1,
                                            __bf16* __restrict__ O1,
                                            const float* __restrict__ W2,
                                            __bf16* __restrict__ O2,
                                            const float* __restrict__ x,
                                            __bf16* __restrict__ x_bf) {
    const int T1 = (TRI_ / 64) * (DIM_ / 64);   // 1728
    const int T2 = (DIM_ / 64) * (DIM_ / 64);   // 576
    int blk = blockIdx.x;
    const int t = threadIdx.x;

    if (blk >= T1 + T2) {                       // cvt x -> bf16
        blk -= T1 + T2;
        int i = blk * 256 + t;
        float4 v = ((const float4*)x)[i];
        bf16x4 o;
        o.x = (__bf16)v.x; o.y = (__bf16)v.y; o.z = (__bf16)v.z; o.w = (__bf16)v.w;
        *(bf16x4*)(x_bf + (size_t)i * 4) = o;
        return;
    }

    const float* in; __bf16* out; int R, C, c0, r0;
    if (blk < T1) {
        in = W1; out = O1; R = DIM_; C = TRI_;
        c0 = (blk % (TRI_ / 64)) * 64; r0 = (blk / (TRI_ / 64)) * 64;
    } else {
        blk -= T1;
        in = W2; out = O2; R = DIM_; C = DIM_;
        c0 = (blk % (DIM_ / 64)) * 64; r0 = (blk / (DIM_ / 64)) * 64;
    }
    __shared__ float tile[64][65];
    const int c4 = t & 15, r = t >> 4;
    #pragma unroll
    for (int i = 0; i < 64; i += 16) {
        float4 v = *(const float4*)&in[(size_t)(r0 + r + i) * C + c0 + c4 * 4];
        tile[r + i][c4 * 4 + 0] = v.x;
        tile[r + i][c4 * 4 + 1] = v.y;
        tile[r + i][c4 * 4 + 2] = v.z;
        tile[r + i][c4 * 4 + 3] = v.w;
    }
    __syncthreads();
    const int cc = t >> 2, ch = t & 3;
    #pragma unroll
    for (int cho = 0; cho < 8; cho += 4) {
        int chh = ch + cho;
        bf16x8 o;
        #pragma unroll
        for (int k = 0; k < 8; ++k) o[k] = (__bf16)tile[chh * 8 + k][cc];
        *(bf16x8*)&out[(size_t)(c0 + cc) * R + r0 + chh * 8] = o;
    }
}

// -------------------- QKV GEMM 128x192, BK=64, single-buffer, 32x32x16 MFMA
// 4 waves each 64x96 as 2x3 of 32x32 frags; 3-bit XOR swizzle (0 conflicts).
// NOTE (round-3 post-mortem): do NOT double-buffer this kernel. 80 KB LDS
// drops residency 3->2 blocks/CU and costs +19 us (occupancy > pipelining
// for this 2-barrier structure; implicit wave overlap per m114 already wins).
__global__ __launch_bounds__(256, 3) void gemm_qkv(const __bf16* __restrict__ A,
                                                   const __bf16* __restrict__ Bt,
                                                   const float*  __restrict__ bias,
                                                   __bf16* __restrict__ Cout,
                                                   int Mdim, int Ndim, int Kdim) {
    __shared__ __align__(16) __bf16 sA[128 * 64];   // 16 KB
    __shared__ __align__(16) __bf16 sB[192 * 64];   // 24 KB

    const int ntiles = Ndim / 192;
    const int tile_n = blockIdx.x % ntiles;
    const int tile_m = blockIdx.x / ntiles;
    const int m0 = tile_m << 7, n0 = tile_n * 192;

    const int tid  = threadIdx.x;
    const int lane = tid & 63;
    const int wave = tid >> 6;
    const int wm = (wave >> 1) * 64;
    const int wn = (wave & 1) * 96;

    floatx16 acc[2][3] = {};

    const int lr8 = lane >> 3;                  // staging row within 8-row group
    const int swz = (((lane & 7) ^ lr8) * 8);   // staging source chunk (swizzled)

    const int m32  = lane & 31;                 // MFMA row/col within 32
    const int half = lane >> 5;                 // k-half selector
    const int lx7  = lane & 7;                  // row&7 for frag reads (rows ≡ lane mod 8)

    for (int k0 = 0; k0 < Kdim; k0 += 64) {
        #pragma unroll
        for (int c = 0; c < 4; ++c) {
            int r0 = wave * 32 + c * 8;
            const __bf16* ga = A + (size_t)(m0 + r0 + lr8) * Kdim + k0 + swz;
            __builtin_amdgcn_global_load_lds((glob_u8*)ga, (lds_u8*)&sA[r0 * 64], 16, 0, 0);
        }
        #pragma unroll
        for (int c = 0; c < 6; ++c) {
            int r0 = wave * 48 + c * 8;
            const __bf16* gb = Bt + (size_t)(n0 + r0 + lr8) * Kdim + k0 + swz;
            __builtin_amdgcn_global_load_lds((glob_u8*)gb, (lds_u8*)&sB[r0 * 64], 16, 0, 0);
        }
        __syncthreads();

        #pragma unroll
        for (int ks = 0; ks < 4; ++ks) {        // 4 k-steps of 16
            const int ko = (((ks * 2 + half) ^ lx7) * 8);
            bf16x8 af[2], bfr[3];
            #pragma unroll
            for (int i = 0; i < 2; ++i)
                af[i] = *(const bf16x8*)&sA[(wm + i * 32 + m32) * 64 + ko];
            #pragma unroll
            for (int j = 0; j < 3; ++j)
                bfr[j] = *(const bf16x8*)&sB[(wn + j * 32 + m32) * 64 + ko];
            #pragma unroll
            for (int i = 0; i < 2; ++i)
                #pragma unroll
                for (int j = 0; j < 3; ++j)
                    acc[i][j] = __builtin_amdgcn_mfma_f32_32x32x16_bf16(af[i], bfr[j], acc[i][j], 0, 0, 0);
        }
        __syncthreads();
    }

    // C/D layout (m74/m101): col = lane&31, row = (reg&3) + 8*(reg>>2) + 4*(lane>>5)
    #pragma unroll
    for (int j = 0; j < 3; ++j) {
        int gc = n0 + wn + j * 32 + m32;
        float bv = bias[gc];
        #pragma unroll
        for (int i = 0; i < 2; ++i) {
            #pragma unroll
            for (int r = 0; r < 16; ++r) {
                int gr = m0 + wm + i * 32 + (r & 3) + 8 * (r >> 2) + 4 * half;
                Cout[(size_t)gr * Ndim + gc] = (__bf16)(acc[i][j][r] + bv);
            }
        }
    }
}

// ---------------- out GEMM: 64x128 tile, BK=64, DOUBLE-buffer 2-phase
// LDS 48 KB -> keeps 3 blocks/CU (grid 768 = 3.0/CU balanced) + overlap.
// (round-3 A/B: this dbuf variant was ~-3.5 us vs BK=128 single-buffer,
//  because occupancy was preserved — contrast with the qkv dbuf failure.)
__global__ __launch_bounds__(256, 3) void gemm_out(const __bf16* __restrict__ A,
                                                   const __bf16* __restrict__ Bt,
                                                   const float*  __restrict__ bias,
                                                   float* __restrict__ Cout,
                                                   int Mdim, int Ndim, int Kdim) {
    __shared__ __align__(16) __bf16 sA[2][64 * 64];    // 16 KB
    __shared__ __align__(16) __bf16 sB[2][128 * 64];   // 32 KB

    const int ntiles = Ndim >> 7;            // 12
    const int tile_n = blockIdx.x % ntiles;
    const int tile_m = blockIdx.x / ntiles;
    const int m0 = tile_m << 6, n0 = tile_n << 7;

    const int tid  = threadIdx.x;
    const int lane = tid & 63;
    const int wave = tid >> 6;
    const int wm = (wave >> 1) * 32;         // 2 wave-rows of 32
    const int wn = (wave & 1) * 64;          // 2 wave-cols of 64

    floatx4 acc[2][4] = {};

    const int lr8 = lane >> 3;
    const int swz = ((lane & 7) ^ lr8) * 8;

    const int row  = lane & 15;
    const int quad = lane >> 4;

    auto stage = [&](int buf, int kk) {
        #pragma unroll
        for (int c = 0; c < 2; ++c) {            // A: 64 rows
            int r0 = wave * 16 + c * 8;
            const __bf16* ga = A + (size_t)(m0 + r0 + lr8) * Kdim + kk + swz;
            __builtin_amdgcn_global_load_lds((glob_u8*)ga, (lds_u8*)&sA[buf][r0 * 64], 16, 0, 0);
        }
        #pragma unroll
        for (int c = 0; c < 4; ++c) {            // B: 128 rows
            int r0 = wave * 32 + c * 8;
            const __bf16* gb = Bt + (size_t)(n0 + r0 + lr8) * Kdim + kk + swz;
            __builtin_amdgcn_global_load_lds((glob_u8*)gb, (lds_u8*)&sB[buf][r0 * 64], 16, 0, 0);
        }
    };

    stage(0, 0);
    for (int k0 = 0; k0 < Kdim; k0 += 64) {
        const int cur = (k0 >> 6) & 1;
        __syncthreads();
        if (k0 + 64 < Kdim) stage(cur ^ 1, k0 + 64);

        #pragma unroll
        for (int ks = 0; ks < 2; ++ks) {
            const int ck = ((ks * 4 + quad) ^ (row & 7)) * 8;
            bf16x8 af[2], bfr[4];
            #pragma unroll
            for (int i = 0; i < 2; ++i)
                af[i]  = *(const bf16x8*)&sA[cur][(wm + i * 16 + row) * 64 + ck];
            #pragma unroll
            for (int j = 0; j < 4; ++j)
                bfr[j] = *(const bf16x8*)&sB[cur][(wn + j * 16 + row) * 64 + ck];
            #pragma unroll
            for (int i = 0; i < 2; ++i)
                #pragma unroll
                for (int j = 0; j < 4; ++j)
                    acc[i][j] = __builtin_amdgcn_mfma_f32_16x16x32_bf16(af[i], bfr[j], acc[i][j], 0, 0, 0);
        }
    }

    #pragma unroll
    for (int j = 0; j < 4; ++j) {
        int gc = n0 + wn + j * 16 + row;
        float bv = bias[gc];
        #pragma unroll
        for (int i = 0; i < 2; ++i) {
            #pragma unroll
            for (int r = 0; r < 4; ++r) {
                int gr = m0 + wm + i * 16 + quad * 4 + r;
                Cout[(size_t)gr * Ndim + gc] = acc[i][j][r] + bv;
            }
        }
    }
}

// ------------------------------------------------------------------ anchor attention
// v2: LDS-tiled. Block = (b, h, 64-query chunk); grid 2*12*32 = 768 blocks, 256 thr.
#define AROWS 86          // 84 halo rows + 2 global rows
#define ATOT  2752        // 2*86*16 chunk-loads of 16B

__global__ __launch_bounds__(256) void anchor_attn(const __bf16* __restrict__ qkv,
                                                   const float* __restrict__ group_scale,
                                                   __bf16* __restrict__ attn_out) {
    const int sc = blockIdx.x;          // 0..31  : 64-query chunk
    const int h  = blockIdx.y;          // 0..11
    const int b  = blockIdx.z;          // 0..1
    const int s0 = sc * 64;

    __shared__ __align__(16) __bf16 sKV[2 * AROWS * 128];   // K then V, 44 KB

    const int tid  = threadIdx.x;
    const int wave = tid >> 6;

    // ---- stage K and V rows (pre-swizzled source, linear LDS dest)
    #pragma unroll
    for (int base = 0; base < ATOT; base += 256) {
        int i = base + tid;
        if (i < ATOT) {
            int r  = i >> 4;                    // 0..171 combined K/V row
            int c  = i & 15;                    // dest 16B chunk
            int kv = (r >= AROWS) ? 1 : 0;
            int rr = r - AROWS * kv;            // 0..85
            int s_row = (rr < 84) ? min(max(s0 - 10 + rr, 0), S_ - 1)
                                  : (rr == 84 ? 0 : S_ - 1);
            int cs = c ^ (rr & 7);              // pre-swizzled source chunk
            const __bf16* src = qkv + (size_t)(b * S_ + s_row) * TRI_
                              + DIM_ * (1 + kv) + h * HD_ + cs * 8;
            __builtin_amdgcn_global_load_lds((glob_u8*)src,
                (lds_u8*)sKV + (size_t)(base + wave * 64) * 16, 16, 0, 0);
        }
    }

    // ---- log group weights (redundant per thread, cheap)
    float g0 = group_scale[0], g1 = group_scale[1], g2 = group_scale[2];
    float gm = fmaxf(g0, fmaxf(g1, g2));
    float e0 = __expf(g0 - gm), e1 = __expf(g1 - gm), e2 = __expf(g2 - gm);
    float ls = __logf(e0 + e1 + e2);
    float lw0 = g0 - gm - ls, lw1 = g1 - gm - ls, lw2 = g2 - gm - ls;

    const int s_local = tid >> 2;       // 0..63
    const int ds      = tid & 3;        // 32-dim slice
    const int s       = s0 + s_local;

    // ---- Q slice -> registers (fp32)
    float q[32];
    {
        const __bf16* qp = qkv + (size_t)(b * S_ + s) * TRI_ + h * HD_ + ds * 32;
        #pragma unroll
        for (int j = 0; j < 4; ++j) {
            bf16x8 qv = *(const bf16x8*)(qp + j * 8);
            #pragma unroll
            for (int k = 0; k < 8; ++k) q[j * 8 + k] = (float)qv[k];
        }
    }

    // anchor LDS slots
    int slot[12];
    const int offs[10] = {-3, -2, -1, 1, 2, 3, -10, -5, 5, 10};
    #pragma unroll
    for (int a = 0; a < 10; ++a) slot[a] = s_local + 10 + offs[a];   // 0..83
    slot[10] = 84; slot[11] = 85;

    __syncthreads();

    const float scale = 0.08838834764831845f;
    float p[12];
    float mx = -1e30f;
    #pragma unroll
    for (int a = 0; a < 12; ++a) {
        const int ro = slot[a] * 128;
        const int sw = slot[a] & 7;
        float d = 0.f;
        #pragma unroll
        for (int j = 0; j < 4; ++j) {
            bf16x8 kv = *(const bf16x8*)&sKV[ro + ((ds * 4 + j) ^ sw) * 8];
            #pragma unroll
            for (int k = 0; k < 8; ++k) d += q[j * 8 + k] * (float)kv[k];
        }
        d += __shfl_xor(d, 1); d += __shfl_xor(d, 2);   // reduce over 4-lane group
        float v = d * scale + (a < 6 ? lw0 : (a < 10 ? lw1 : lw2));
        p[a] = v;
        mx = fmaxf(mx, v);
    }
    float l = 0.f;
    #pragma unroll
    for (int a = 0; a < 12; ++a) { p[a] = __expf(p[a] - mx); l += p[a]; }
    float inv = 1.0f / l;

    float o[32] = {};
    #pragma unroll
    for (int a = 0; a < 12; ++a) {
        const int ro = AROWS * 128 + slot[a] * 128;
        const int sw = slot[a] & 7;
        float pa = p[a];
        #pragma unroll
        for (int j = 0; j < 4; ++j) {
            bf16x8 vv = *(const bf16x8*)&sKV[ro + ((ds * 4 + j) ^ sw) * 8];
            #pragma unroll
            for (int k = 0; k < 8; ++k) o[j * 8 + k] += pa * (float)vv[k];
        }
    }

    __bf16* op = attn_out + (size_t)(b * S_ + s) * DIM_ + h * HD_ + ds * 32;
    #pragma unroll
    for (int j = 0; j < 4; ++j) {
        bf16x8 ov;
        #pragma unroll
        for (int k = 0; k < 8; ++k) ov[k] = (__bf16)(o[j * 8 + k] * inv);
        *(bf16x8*)(op + j * 8) = ov;
    }
}

// ----------------------------------------------------------------------- launcher
extern "C" void kernel_launch(void* const* d_in, const int* in_sizes, int n_in,
                              void* d_out, int out_size, void* d_ws, size_t ws_size,
                              hipStream_t stream) {
    const float* x    = (const float*)d_in[0];
    const float* Wqkv = (const float*)d_in[1];
    const float* bqkv = (const float*)d_in[2];
    const float* Wout = (const float*)d_in[3];
    const float* bout = (const float*)d_in[4];
    const float* gsc  = (const float*)d_in[5];
    float* out = (float*)d_out;

    char* ws = (char*)d_ws;
    __bf16* x_bf   = (__bf16*)(ws);
    __bf16* WqkvT  = (__bf16*)(ws + 12582912);
    __bf16* WoutT  = (__bf16*)(ws + 12582912 + 14155776);
    __bf16* qkv    = (__bf16*)(ws + 12582912 + 14155776 + 4718592);
    __bf16* attn   = (__bf16*)(ws + 12582912 + 14155776 + 4718592 + 37748736);

    // prep: transposes + cvt (one launch)
    {
        int nblk = (TRI_ / 64) * (DIM_ / 64) + (DIM_ / 64) * (DIM_ / 64)
                 + (M_ * DIM_) / 1024;
        prep<<<nblk, 256, 0, stream>>>(Wqkv, WqkvT, Wout, WoutT, x, x_bf);
    }

    // QKV GEMM: 128x192 tiles -> 768 blocks (3.0/CU), single-buffer
    gemm_qkv<<<(M_ / 128) * (TRI_ / 192), 256, 0, stream>>>(
        x_bf, WqkvT, bqkv, qkv, M_, TRI_, DIM_);

    // anchor attention v2: LDS-tiled, grid (32, 12, 2)
    anchor_attn<<<dim3(32, H_, B_), 256, 0, stream>>>(qkv, gsc, attn);

    // out GEMM: 64x128 tiles, BK=64 dbuf 2-phase -> 768 blocks (3.0/CU)
    gemm_out<<<(M_ / 64) * (DIM_ / 128), 256, 0, stream>>>(
        attn, WoutT, bout, out, M_, DIM_, DIM_);
}

// Round 5
// 209.243 us; speedup vs baseline: 1.0801x; 1.0373x over previous
//
#include <hip/hip_runtime.h>
#include <hip/hip_bf16.h>
#include <cstdint>
#include <math.h>

#define B_    2
#define S_    2048
#define DIM_  1536
#define H_    12
#define HD_   128
#define TRI_  4608   // 3*DIM
#define M_    4096   // B*S

typedef __attribute__((ext_vector_type(8)))  __bf16 bf16x8;
typedef __attribute__((ext_vector_type(4)))  __bf16 bf16x4;
typedef __attribute__((ext_vector_type(4)))  float  floatx4;
typedef __attribute__((ext_vector_type(16))) float  floatx16;

typedef __attribute__((address_space(3))) uint8_t       lds_u8;
typedef const __attribute__((address_space(1))) uint8_t glob_u8;

// ---------------- prep: W1/W2 transpose+cvt, x cvt — one launch
__global__ __launch_bounds__(256) void prep(const float* __restrict__ W1,
                                            __bf16* __restrict__ O1,
                                            const float* __restrict__ W2,
                                            __bf16* __restrict__ O2,
                                            const float* __restrict__ x,
                                            __bf16* __restrict__ x_bf) {
    const int T1 = (TRI_ / 64) * (DIM_ / 64);   // 1728
    const int T2 = (DIM_ / 64) * (DIM_ / 64);   // 576
    int blk = blockIdx.x;
    const int t = threadIdx.x;

    if (blk >= T1 + T2) {                       // cvt x -> bf16
        blk -= T1 + T2;
        int i = blk * 256 + t;
        float4 v = ((const float4*)x)[i];
        bf16x4 o;
        o.x = (__bf16)v.x; o.y = (__bf16)v.y; o.z = (__bf16)v.z; o.w = (__bf16)v.w;
        *(bf16x4*)(x_bf + (size_t)i * 4) = o;
        return;
    }

    const float* in; __bf16* out; int R, C, c0, r0;
    if (blk < T1) {
        in = W1; out = O1; R = DIM_; C = TRI_;
        c0 = (blk % (TRI_ / 64)) * 64; r0 = (blk / (TRI_ / 64)) * 64;
    } else {
        blk -= T1;
        in = W2; out = O2; R = DIM_; C = DIM_;
        c0 = (blk % (DIM_ / 64)) * 64; r0 = (blk / (DIM_ / 64)) * 64;
    }
    __shared__ float tile[64][65];
    const int c4 = t & 15, r = t >> 4;
    #pragma unroll
    for (int i = 0; i < 64; i += 16) {
        float4 v = *(const float4*)&in[(size_t)(r0 + r + i) * C + c0 + c4 * 4];
        tile[r + i][c4 * 4 + 0] = v.x;
        tile[r + i][c4 * 4 + 1] = v.y;
        tile[r + i][c4 * 4 + 2] = v.z;
        tile[r + i][c4 * 4 + 3] = v.w;
    }
    __syncthreads();
    const int cc = t >> 2, ch = t & 3;
    #pragma unroll
    for (int cho = 0; cho < 8; cho += 4) {
        int chh = ch + cho;
        bf16x8 o;
        #pragma unroll
        for (int k = 0; k < 8; ++k) o[k] = (__bf16)tile[chh * 8 + k][cc];
        *(bf16x8*)&out[(size_t)(c0 + cc) * R + r0 + chh * 8] = o;
    }
}

// -------------------- QKV GEMM 128x192, BK=64, single-buffer, 32x32x16 MFMA
// 4 waves each 64x96 as 2x3 of 32x32 frags; 3-bit XOR swizzle (0 conflicts).
// NOTE (round-3 post-mortem): do NOT double-buffer this kernel. 80 KB LDS
// drops residency 3->2 blocks/CU and costs +19 us (occupancy > pipelining
// for this 2-barrier structure; implicit wave overlap per m114 already wins).
// round-5: + XCD-chunked blockIdx swizzle (768 % 8 == 0 -> bijective) so each
// XCD's 96 contiguous tiles (4 m-rows) reuse A-panels in its private L2.
__global__ __launch_bounds__(256, 3) void gemm_qkv(const __bf16* __restrict__ A,
                                                   const __bf16* __restrict__ Bt,
                                                   const float*  __restrict__ bias,
                                                   __bf16* __restrict__ Cout,
                                                   int Mdim, int Ndim, int Kdim) {
    __shared__ __align__(16) __bf16 sA[128 * 64];   // 16 KB
    __shared__ __align__(16) __bf16 sB[192 * 64];   // 24 KB

    const int ntiles = Ndim / 192;
    int bid = blockIdx.x;
    const int cpx = gridDim.x >> 3;                 // grid is a multiple of 8
    bid = (bid & 7) * cpx + (bid >> 3);             // XCD-chunked remap
    const int tile_n = bid % ntiles;
    const int tile_m = bid / ntiles;
    const int m0 = tile_m << 7, n0 = tile_n * 192;

    const int tid  = threadIdx.x;
    const int lane = tid & 63;
    const int wave = tid >> 6;
    const int wm = (wave >> 1) * 64;
    const int wn = (wave & 1) * 96;

    floatx16 acc[2][3] = {};

    const int lr8 = lane >> 3;                  // staging row within 8-row group
    const int swz = (((lane & 7) ^ lr8) * 8);   // staging source chunk (swizzled)

    const int m32  = lane & 31;                 // MFMA row/col within 32
    const int half = lane >> 5;                 // k-half selector
    const int lx7  = lane & 7;                  // row&7 for frag reads (rows ≡ lane mod 8)

    for (int k0 = 0; k0 < Kdim; k0 += 64) {
        #pragma unroll
        for (int c = 0; c < 4; ++c) {
            int r0 = wave * 32 + c * 8;
            const __bf16* ga = A + (size_t)(m0 + r0 + lr8) * Kdim + k0 + swz;
            __builtin_amdgcn_global_load_lds((glob_u8*)ga, (lds_u8*)&sA[r0 * 64], 16, 0, 0);
        }
        #pragma unroll
        for (int c = 0; c < 6; ++c) {
            int r0 = wave * 48 + c * 8;
            const __bf16* gb = Bt + (size_t)(n0 + r0 + lr8) * Kdim + k0 + swz;
            __builtin_amdgcn_global_load_lds((glob_u8*)gb, (lds_u8*)&sB[r0 * 64], 16, 0, 0);
        }
        __syncthreads();

        #pragma unroll
        for (int ks = 0; ks < 4; ++ks) {        // 4 k-steps of 16
            const int ko = (((ks * 2 + half) ^ lx7) * 8);
            bf16x8 af[2], bfr[3];
            #pragma unroll
            for (int i = 0; i < 2; ++i)
                af[i] = *(const bf16x8*)&sA[(wm + i * 32 + m32) * 64 + ko];
            #pragma unroll
            for (int j = 0; j < 3; ++j)
                bfr[j] = *(const bf16x8*)&sB[(wn + j * 32 + m32) * 64 + ko];
            #pragma unroll
            for (int i = 0; i < 2; ++i)
                #pragma unroll
                for (int j = 0; j < 3; ++j)
                    acc[i][j] = __builtin_amdgcn_mfma_f32_32x32x16_bf16(af[i], bfr[j], acc[i][j], 0, 0, 0);
        }
        __syncthreads();
    }

    // C/D layout (m74/m101): col = lane&31, row = (reg&3) + 8*(reg>>2) + 4*(lane>>5)
    #pragma unroll
    for (int j = 0; j < 3; ++j) {
        int gc = n0 + wn + j * 32 + m32;
        float bv = bias[gc];
        #pragma unroll
        for (int i = 0; i < 2; ++i) {
            #pragma unroll
            for (int r = 0; r < 16; ++r) {
                int gr = m0 + wm + i * 32 + (r & 3) + 8 * (r >> 2) + 4 * half;
                Cout[(size_t)gr * Ndim + gc] = (__bf16)(acc[i][j][r] + bv);
            }
        }
    }
}

// ---------------- out GEMM: 64x128 tile, BK=128, single-buffer (round-2 config)
// 48 KB LDS -> 3 blocks/CU, grid 768 = 3.0/CU balanced. 4-bit XOR swizzle.
// NOTE (round-4 post-mortem): BK=64 dbuf variant was +7 us — same barrier
// count but each vmcnt(0) drain covered by only ~16 MFMA. Keep this form.
// round-5: + XCD-chunked blockIdx swizzle (768 % 8 == 0).
__global__ __launch_bounds__(256, 3) void gemm_out(const __bf16* __restrict__ A,
                                                   const __bf16* __restrict__ Bt,
                                                   const float*  __restrict__ bias,
                                                   float* __restrict__ Cout,
                                                   int Mdim, int Ndim, int Kdim) {
    __shared__ __align__(16) __bf16 sA[64 * 128];    // 16 KB
    __shared__ __align__(16) __bf16 sB[128 * 128];   // 32 KB

    const int ntiles = Ndim >> 7;            // 12
    int bid = blockIdx.x;
    const int cpx = gridDim.x >> 3;          // 96
    bid = (bid & 7) * cpx + (bid >> 3);      // XCD-chunked remap
    const int tile_n = bid % ntiles;
    const int tile_m = bid / ntiles;
    const int m0 = tile_m << 6, n0 = tile_n << 7;

    const int tid  = threadIdx.x;
    const int lane = tid & 63;
    const int wave = tid >> 6;
    const int wm = (wave >> 1) * 32;         // 2 wave-rows of 32
    const int wn = (wave & 1) * 64;          // 2 wave-cols of 64

    floatx4 acc[2][4] = {};

    const int lr4 = lane >> 4;          // 0..3 : row within 4-row DMA group
    const int lc  = lane & 15;          // 16B-chunk slot
    int swz[4];
    #pragma unroll
    for (int v = 0; v < 4; ++v) swz[v] = (lc ^ (v * 4 + lr4)) * 8;  // elems

    const int row  = lane & 15;
    const int quad = lane >> 4;

    for (int k0 = 0; k0 < Kdim; k0 += 128) {
        #pragma unroll
        for (int c = 0; c < 4; ++c) {            // A: 64 rows
            int r0 = wave * 16 + c * 4;          // wave-uniform base row
            const __bf16* ga = A + (size_t)(m0 + r0 + lr4) * Kdim + k0 + swz[c & 3];
            __builtin_amdgcn_global_load_lds((glob_u8*)ga, (lds_u8*)&sA[r0 * 128], 16, 0, 0);
        }
        #pragma unroll
        for (int c = 0; c < 8; ++c) {            // B: 128 rows
            int r0 = wave * 32 + c * 4;
            const __bf16* gb = Bt + (size_t)(n0 + r0 + lr4) * Kdim + k0 + swz[c & 3];
            __builtin_amdgcn_global_load_lds((glob_u8*)gb, (lds_u8*)&sB[r0 * 128], 16, 0, 0);
        }
        __syncthreads();

        #pragma unroll
        for (int ks = 0; ks < 4; ++ks) {
            const int ck = ((ks * 4 + quad) ^ row) * 8;
            bf16x8 af[2], bfr[4];
            #pragma unroll
            for (int i = 0; i < 2; ++i)
                af[i]  = *(const bf16x8*)&sA[(wm + i * 16 + row) * 128 + ck];
            #pragma unroll
            for (int j = 0; j < 4; ++j)
                bfr[j] = *(const bf16x8*)&sB[(wn + j * 16 + row) * 128 + ck];
            #pragma unroll
            for (int i = 0; i < 2; ++i)
                #pragma unroll
                for (int j = 0; j < 4; ++j)
                    acc[i][j] = __builtin_amdgcn_mfma_f32_16x16x32_bf16(af[i], bfr[j], acc[i][j], 0, 0, 0);
        }
        __syncthreads();
    }

    #pragma unroll
    for (int j = 0; j < 4; ++j) {
        int gc = n0 + wn + j * 16 + row;
        float bv = bias[gc];
        #pragma unroll
        for (int i = 0; i < 2; ++i) {
            #pragma unroll
            for (int r = 0; r < 4; ++r) {
                int gr = m0 + wm + i * 16 + quad * 4 + r;
                Cout[(size_t)gr * Ndim + gc] = acc[i][j][r] + bv;
            }
        }
    }
}

// ------------------------------------------------------------------ anchor attention
// v2: LDS-tiled. Block = (b, h, 64-query chunk); grid 2*12*32 = 768 blocks, 256 thr.
#define AROWS 86          // 84 halo rows + 2 global rows
#define ATOT  2752        // 2*86*16 chunk-loads of 16B

__global__ __launch_bounds__(256) void anchor_attn(const __bf16* __restrict__ qkv,
                                                   const float* __restrict__ group_scale,
                                                   __bf16* __restrict__ attn_out) {
    const int sc = blockIdx.x;          // 0..31  : 64-query chunk
    const int h  = blockIdx.y;          // 0..11
    const int b  = blockIdx.z;          // 0..1
    const int s0 = sc * 64;

    __shared__ __align__(16) __bf16 sKV[2 * AROWS * 128];   // K then V, 44 KB

    const int tid  = threadIdx.x;
    const int wave = tid >> 6;

    // ---- stage K and V rows (pre-swizzled source, linear LDS dest)
    #pragma unroll
    for (int base = 0; base < ATOT; base += 256) {
        int i = base + tid;
        if (i < ATOT) {
            int r  = i >> 4;                    // 0..171 combined K/V row
            int c  = i & 15;                    // dest 16B chunk
            int kv = (r >= AROWS) ? 1 : 0;
            int rr = r - AROWS * kv;            // 0..85
            int s_row = (rr < 84) ? min(max(s0 - 10 + rr, 0), S_ - 1)
                                  : (rr == 84 ? 0 : S_ - 1);
            int cs = c ^ (rr & 7);              // pre-swizzled source chunk
            const __bf16* src = qkv + (size_t)(b * S_ + s_row) * TRI_
                              + DIM_ * (1 + kv) + h * HD_ + cs * 8;
            __builtin_amdgcn_global_load_lds((glob_u8*)src,
                (lds_u8*)sKV + (size_t)(base + wave * 64) * 16, 16, 0, 0);
        }
    }

    // ---- log group weights (redundant per thread, cheap)
    float g0 = group_scale[0], g1 = group_scale[1], g2 = group_scale[2];
    float gm = fmaxf(g0, fmaxf(g1, g2));
    float e0 = __expf(g0 - gm), e1 = __expf(g1 - gm), e2 = __expf(g2 - gm);
    float ls = __logf(e0 + e1 + e2);
    float lw0 = g0 - gm - ls, lw1 = g1 - gm - ls, lw2 = g2 - gm - ls;

    const int s_local = tid >> 2;       // 0..63
    const int ds      = tid & 3;        // 32-dim slice
    const int s       = s0 + s_local;

    // ---- Q slice -> registers (fp32)
    float q[32];
    {
        const __bf16* qp = qkv + (size_t)(b * S_ + s) * TRI_ + h * HD_ + ds * 32;
        #pragma unroll
        for (int j = 0; j < 4; ++j) {
            bf16x8 qv = *(const bf16x8*)(qp + j * 8);
            #pragma unroll
            for (int k = 0; k < 8; ++k) q[j * 8 + k] = (float)qv[k];
        }
    }

    // anchor LDS slots
    int slot[12];
    const int offs[10] = {-3, -2, -1, 1, 2, 3, -10, -5, 5, 10};
    #pragma unroll
    for (int a = 0; a < 10; ++a) slot[a] = s_local + 10 + offs[a];   // 0..83
    slot[10] = 84; slot[11] = 85;

    __syncthreads();

    const float scale = 0.08838834764831845f;
    float p[12];
    float mx = -1e30f;
    #pragma unroll
    for (int a = 0; a < 12; ++a) {
        const int ro = slot[a] * 128;
        const int sw = slot[a] & 7;
        float d = 0.f;
        #pragma unroll
        for (int j = 0; j < 4; ++j) {
            bf16x8 kv = *(const bf16x8*)&sKV[ro + ((ds * 4 + j) ^ sw) * 8];
            #pragma unroll
            for (int k = 0; k < 8; ++k) d += q[j * 8 + k] * (float)kv[k];
        }
        d += __shfl_xor(d, 1); d += __shfl_xor(d, 2);   // reduce over 4-lane group
        float v = d * scale + (a < 6 ? lw0 : (a < 10 ? lw1 : lw2));
        p[a] = v;
        mx = fmaxf(mx, v);
    }
    float l = 0.f;
    #pragma unroll
    for (int a = 0; a < 12; ++a) { p[a] = __expf(p[a] - mx); l += p[a]; }
    float inv = 1.0f / l;

    float o[32] = {};
    #pragma unroll
    for (int a = 0; a < 12; ++a) {
        const int ro = AROWS * 128 + slot[a] * 128;
        const int sw = slot[a] & 7;
        float pa = p[a];
        #pragma unroll
        for (int j = 0; j < 4; ++j) {
            bf16x8 vv = *(const bf16x8*)&sKV[ro + ((ds * 4 + j) ^ sw) * 8];
            #pragma unroll
            for (int k = 0; k < 8; ++k) o[j * 8 + k] += pa * (float)vv[k];
        }
    }

    __bf16* op = attn_out + (size_t)(b * S_ + s) * DIM_ + h * HD_ + ds * 32;
    #pragma unroll
    for (int j = 0; j < 4; ++j) {
        bf16x8 ov;
        #pragma unroll
        for (int k = 0; k < 8; ++k) ov[k] = (__bf16)(o[j * 8 + k] * inv);
        *(bf16x8*)(op + j * 8) = ov;
    }
}

// ----------------------------------------------------------------------- launcher
extern "C" void kernel_launch(void* const* d_in, const int* in_sizes, int n_in,
                              void* d_out, int out_size, void* d_ws, size_t ws_size,
                              hipStream_t stream) {
    const float* x    = (const float*)d_in[0];
    const float* Wqkv = (const float*)d_in[1];
    const float* bqkv = (const float*)d_in[2];
    const float* Wout = (const float*)d_in[3];
    const float* bout = (const float*)d_in[4];
    const float* gsc  = (const float*)d_in[5];
    float* out = (float*)d_out;

    char* ws = (char*)d_ws;
    __bf16* x_bf   = (__bf16*)(ws);
    __bf16* WqkvT  = (__bf16*)(ws + 12582912);
    __bf16* WoutT  = (__bf16*)(ws + 12582912 + 14155776);
    __bf16* qkv    = (__bf16*)(ws + 12582912 + 14155776 + 4718592);
    __bf16* attn   = (__bf16*)(ws + 12582912 + 14155776 + 4718592 + 37748736);

    // prep: transposes + cvt (one launch)
    {
        int nblk = (TRI_ / 64) * (DIM_ / 64) + (DIM_ / 64) * (DIM_ / 64)
                 + (M_ * DIM_) / 1024;
        prep<<<nblk, 256, 0, stream>>>(Wqkv, WqkvT, Wout, WoutT, x, x_bf);
    }

    // QKV GEMM: 128x192 tiles -> 768 blocks (3.0/CU), single-buffer + XCD swizzle
    gemm_qkv<<<(M_ / 128) * (TRI_ / 192), 256, 0, stream>>>(
        x_bf, WqkvT, bqkv, qkv, M_, TRI_, DIM_);

    // anchor attention v2: LDS-tiled, grid (32, 12, 2)
    anchor_attn<<<dim3(32, H_, B_), 256, 0, stream>>>(qkv, gsc, attn);

    // out GEMM: 64x128 tiles, BK=128 single-buffer + XCD swizzle -> 768 blocks
    gemm_out<<<(M_ / 64) * (DIM_ / 128), 256, 0, stream>>>(
        attn, WoutT, bout, out, M_, DIM_, DIM_);
}

// Round 6
// 206.234 us; speedup vs baseline: 1.0959x; 1.0146x over previous
//
#include <hip/hip_runtime.h>
#include <hip/hip_bf16.h>
#include <cstdint>
#include <math.h>

#define B_    2
#define S_    2048
#define DIM_  1536
#define H_    12
#define HD_   128
#define TRI_  4608   // 3*DIM
#define M_    4096   // B*S

typedef __attribute__((ext_vector_type(8)))  __bf16 bf16x8;
typedef __attribute__((ext_vector_type(4)))  __bf16 bf16x4;
typedef __attribute__((ext_vector_type(4)))  float  floatx4;
typedef __attribute__((ext_vector_type(16))) float  floatx16;

typedef __attribute__((address_space(3))) uint8_t       lds_u8;
typedef const __attribute__((address_space(1))) uint8_t glob_u8;

// ---------------- prep: W1/W2 transpose+cvt, x cvt — one launch
__global__ __launch_bounds__(256) void prep(const float* __restrict__ W1,
                                            __bf16* __restrict__ O1,
                                            const float* __restrict__ W2,
                                            __bf16* __restrict__ O2,
                                            const float* __restrict__ x,
                                            __bf16* __restrict__ x_bf) {
    const int T1 = (TRI_ / 64) * (DIM_ / 64);   // 1728
    const int T2 = (DIM_ / 64) * (DIM_ / 64);   // 576
    int blk = blockIdx.x;
    const int t = threadIdx.x;

    if (blk >= T1 + T2) {                       // cvt x -> bf16
        blk -= T1 + T2;
        int i = blk * 256 + t;
        float4 v = ((const float4*)x)[i];
        bf16x4 o;
        o.x = (__bf16)v.x; o.y = (__bf16)v.y; o.z = (__bf16)v.z; o.w = (__bf16)v.w;
        *(bf16x4*)(x_bf + (size_t)i * 4) = o;
        return;
    }

    const float* in; __bf16* out; int R, C, c0, r0;
    if (blk < T1) {
        in = W1; out = O1; R = DIM_; C = TRI_;
        c0 = (blk % (TRI_ / 64)) * 64; r0 = (blk / (TRI_ / 64)) * 64;
    } else {
        blk -= T1;
        in = W2; out = O2; R = DIM_; C = DIM_;
        c0 = (blk % (DIM_ / 64)) * 64; r0 = (blk / (DIM_ / 64)) * 64;
    }
    __shared__ float tile[64][65];
    const int c4 = t & 15, r = t >> 4;
    #pragma unroll
    for (int i = 0; i < 64; i += 16) {
        float4 v = *(const float4*)&in[(size_t)(r0 + r + i) * C + c0 + c4 * 4];
        tile[r + i][c4 * 4 + 0] = v.x;
        tile[r + i][c4 * 4 + 1] = v.y;
        tile[r + i][c4 * 4 + 2] = v.z;
        tile[r + i][c4 * 4 + 3] = v.w;
    }
    __syncthreads();
    const int cc = t >> 2, ch = t & 3;
    #pragma unroll
    for (int cho = 0; cho < 8; cho += 4) {
        int chh = ch + cho;
        bf16x8 o;
        #pragma unroll
        for (int k = 0; k < 8; ++k) o[k] = (__bf16)tile[chh * 8 + k][cc];
        *(bf16x8*)&out[(size_t)(c0 + cc) * R + r0 + chh * 8] = o;
    }
}

// -------------------- QKV GEMM 128x192, BK=64, single-buffer, 32x32x16 MFMA
// 4 waves each 64x96 as 2x3 of 32x32 frags; 3-bit XOR swizzle (0 conflicts).
// NOTE (round-3): do NOT double-buffer — 80 KB LDS drops 3->2 blocks/CU,
// +19 us (occupancy > pipelining for this 2-barrier structure).
// NOTE (round-5): do NOT XCD-swizzle this kernel. ntiles=24 ≡ 0 (mod 8), so
// the DEFAULT mapping already gives each XCD a fixed tile_n set {x,x+8,x+16}
// (1.7 MB B-slice, L2-resident) with A-panels shared via L3. The chunked
// remap streamed all 14 MB of B through each XCD's L2: FETCH 57->78 MB,
// dur 64.8->73.4 us. Rule: XCD-swizzle helps iff ntiles % 8 != 0.
__global__ __launch_bounds__(256, 3) void gemm_qkv(const __bf16* __restrict__ A,
                                                   const __bf16* __restrict__ Bt,
                                                   const float*  __restrict__ bias,
                                                   __bf16* __restrict__ Cout,
                                                   int Mdim, int Ndim, int Kdim) {
    __shared__ __align__(16) __bf16 sA[128 * 64];   // 16 KB
    __shared__ __align__(16) __bf16 sB[192 * 64];   // 24 KB

    const int ntiles = Ndim / 192;
    const int tile_n = blockIdx.x % ntiles;
    const int tile_m = blockIdx.x / ntiles;
    const int m0 = tile_m << 7, n0 = tile_n * 192;

    const int tid  = threadIdx.x;
    const int lane = tid & 63;
    const int wave = tid >> 6;
    const int wm = (wave >> 1) * 64;
    const int wn = (wave & 1) * 96;

    floatx16 acc[2][3] = {};

    const int lr8 = lane >> 3;                  // staging row within 8-row group
    const int swz = (((lane & 7) ^ lr8) * 8);   // staging source chunk (swizzled)

    const int m32  = lane & 31;                 // MFMA row/col within 32
    const int half = lane >> 5;                 // k-half selector
    const int lx7  = lane & 7;                  // row&7 for frag reads (rows ≡ lane mod 8)

    for (int k0 = 0; k0 < Kdim; k0 += 64) {
        #pragma unroll
        for (int c = 0; c < 4; ++c) {
            int r0 = wave * 32 + c * 8;
            const __bf16* ga = A + (size_t)(m0 + r0 + lr8) * Kdim + k0 + swz;
            __builtin_amdgcn_global_load_lds((glob_u8*)ga, (lds_u8*)&sA[r0 * 64], 16, 0, 0);
        }
        #pragma unroll
        for (int c = 0; c < 6; ++c) {
            int r0 = wave * 48 + c * 8;
            const __bf16* gb = Bt + (size_t)(n0 + r0 + lr8) * Kdim + k0 + swz;
            __builtin_amdgcn_global_load_lds((glob_u8*)gb, (lds_u8*)&sB[r0 * 64], 16, 0, 0);
        }
        __syncthreads();

        #pragma unroll
        for (int ks = 0; ks < 4; ++ks) {        // 4 k-steps of 16
            const int ko = (((ks * 2 + half) ^ lx7) * 8);
            bf16x8 af[2], bfr[3];
            #pragma unroll
            for (int i = 0; i < 2; ++i)
                af[i] = *(const bf16x8*)&sA[(wm + i * 32 + m32) * 64 + ko];
            #pragma unroll
            for (int j = 0; j < 3; ++j)
                bfr[j] = *(const bf16x8*)&sB[(wn + j * 32 + m32) * 64 + ko];
            #pragma unroll
            for (int i = 0; i < 2; ++i)
                #pragma unroll
                for (int j = 0; j < 3; ++j)
                    acc[i][j] = __builtin_amdgcn_mfma_f32_32x32x16_bf16(af[i], bfr[j], acc[i][j], 0, 0, 0);
        }
        __syncthreads();
    }

    // C/D layout (m74/m101): col = lane&31, row = (reg&3) + 8*(reg>>2) + 4*(lane>>5)
    #pragma unroll
    for (int j = 0; j < 3; ++j) {
        int gc = n0 + wn + j * 32 + m32;
        float bv = bias[gc];
        #pragma unroll
        for (int i = 0; i < 2; ++i) {
            #pragma unroll
            for (int r = 0; r < 16; ++r) {
                int gr = m0 + wm + i * 32 + (r & 3) + 8 * (r >> 2) + 4 * half;
                Cout[(size_t)gr * Ndim + gc] = (__bf16)(acc[i][j][r] + bv);
            }
        }
    }
}

// ---------------- out GEMM: 64x128 tile, BK=128, single-buffer (round-2 config)
// 48 KB LDS -> 3 blocks/CU, grid 768 = 3.0/CU balanced. 4-bit XOR swizzle.
// NOTE (round-4): BK=64 dbuf variant was +7 us — same barrier count but each
// vmcnt(0) drain covered by only ~16 MFMA. Keep this form.
// round-5 KEPT: XCD-chunked swizzle. ntiles=12 (12 % 8 != 0) so default
// mapping rotates B-columns across XCDs; chunking gave ~-8.5 us (A-panel +
// B mostly L2/L3-resident per XCD).
__global__ __launch_bounds__(256, 3) void gemm_out(const __bf16* __restrict__ A,
                                                   const __bf16* __restrict__ Bt,
                                                   const float*  __restrict__ bias,
                                                   float* __restrict__ Cout,
                                                   int Mdim, int Ndim, int Kdim) {
    __shared__ __align__(16) __bf16 sA[64 * 128];    // 16 KB
    __shared__ __align__(16) __bf16 sB[128 * 128];   // 32 KB

    const int ntiles = Ndim >> 7;            // 12
    int bid = blockIdx.x;
    const int cpx = gridDim.x >> 3;          // 96
    bid = (bid & 7) * cpx + (bid >> 3);      // XCD-chunked remap
    const int tile_n = bid % ntiles;
    const int tile_m = bid / ntiles;
    const int m0 = tile_m << 6, n0 = tile_n << 7;

    const int tid  = threadIdx.x;
    const int lane = tid & 63;
    const int wave = tid >> 6;
    const int wm = (wave >> 1) * 32;         // 2 wave-rows of 32
    const int wn = (wave & 1) * 64;          // 2 wave-cols of 64

    floatx4 acc[2][4] = {};

    const int lr4 = lane >> 4;          // 0..3 : row within 4-row DMA group
    const int lc  = lane & 15;          // 16B-chunk slot
    int swz[4];
    #pragma unroll
    for (int v = 0; v < 4; ++v) swz[v] = (lc ^ (v * 4 + lr4)) * 8;  // elems

    const int row  = lane & 15;
    const int quad = lane >> 4;

    for (int k0 = 0; k0 < Kdim; k0 += 128) {
        #pragma unroll
        for (int c = 0; c < 4; ++c) {            // A: 64 rows
            int r0 = wave * 16 + c * 4;          // wave-uniform base row
            const __bf16* ga = A + (size_t)(m0 + r0 + lr4) * Kdim + k0 + swz[c & 3];
            __builtin_amdgcn_global_load_lds((glob_u8*)ga, (lds_u8*)&sA[r0 * 128], 16, 0, 0);
        }
        #pragma unroll
        for (int c = 0; c < 8; ++c) {            // B: 128 rows
            int r0 = wave * 32 + c * 4;
            const __bf16* gb = Bt + (size_t)(n0 + r0 + lr4) * Kdim + k0 + swz[c & 3];
            __builtin_amdgcn_global_load_lds((glob_u8*)gb, (lds_u8*)&sB[r0 * 128], 16, 0, 0);
        }
        __syncthreads();

        #pragma unroll
        for (int ks = 0; ks < 4; ++ks) {
            const int ck = ((ks * 4 + quad) ^ row) * 8;
            bf16x8 af[2], bfr[4];
            #pragma unroll
            for (int i = 0; i < 2; ++i)
                af[i]  = *(const bf16x8*)&sA[(wm + i * 16 + row) * 128 + ck];
            #pragma unroll
            for (int j = 0; j < 4; ++j)
                bfr[j] = *(const bf16x8*)&sB[(wn + j * 16 + row) * 128 + ck];
            #pragma unroll
            for (int i = 0; i < 2; ++i)
                #pragma unroll
                for (int j = 0; j < 4; ++j)
                    acc[i][j] = __builtin_amdgcn_mfma_f32_16x16x32_bf16(af[i], bfr[j], acc[i][j], 0, 0, 0);
        }
        __syncthreads();
    }

    #pragma unroll
    for (int j = 0; j < 4; ++j) {
        int gc = n0 + wn + j * 16 + row;
        float bv = bias[gc];
        #pragma unroll
        for (int i = 0; i < 2; ++i) {
            #pragma unroll
            for (int r = 0; r < 4; ++r) {
                int gr = m0 + wm + i * 16 + quad * 4 + r;
                Cout[(size_t)gr * Ndim + gc] = acc[i][j][r] + bv;
            }
        }
    }
}

// ------------------------------------------------------------------ anchor attention
// v2: LDS-tiled. Block = (b, h, 64-query chunk); grid 2*12*32 = 768 blocks, 256 thr.
#define AROWS 86          // 84 halo rows + 2 global rows
#define ATOT  2752        // 2*86*16 chunk-loads of 16B

__global__ __launch_bounds__(256) void anchor_attn(const __bf16* __restrict__ qkv,
                                                   const float* __restrict__ group_scale,
                                                   __bf16* __restrict__ attn_out) {
    const int sc = blockIdx.x;          // 0..31  : 64-query chunk
    const int h  = blockIdx.y;          // 0..11
    const int b  = blockIdx.z;          // 0..1
    const int s0 = sc * 64;

    __shared__ __align__(16) __bf16 sKV[2 * AROWS * 128];   // K then V, 44 KB

    const int tid  = threadIdx.x;
    const int wave = tid >> 6;

    // ---- stage K and V rows (pre-swizzled source, linear LDS dest)
    #pragma unroll
    for (int base = 0; base < ATOT; base += 256) {
        int i = base + tid;
        if (i < ATOT) {
            int r  = i >> 4;                    // 0..171 combined K/V row
            int c  = i & 15;                    // dest 16B chunk
            int kv = (r >= AROWS) ? 1 : 0;
            int rr = r - AROWS * kv;            // 0..85
            int s_row = (rr < 84) ? min(max(s0 - 10 + rr, 0), S_ - 1)
                                  : (rr == 84 ? 0 : S_ - 1);
            int cs = c ^ (rr & 7);              // pre-swizzled source chunk
            const __bf16* src = qkv + (size_t)(b * S_ + s_row) * TRI_
                              + DIM_ * (1 + kv) + h * HD_ + cs * 8;
            __builtin_amdgcn_global_load_lds((glob_u8*)src,
                (lds_u8*)sKV + (size_t)(base + wave * 64) * 16, 16, 0, 0);
        }
    }

    // ---- log group weights (redundant per thread, cheap)
    float g0 = group_scale[0], g1 = group_scale[1], g2 = group_scale[2];
    float gm = fmaxf(g0, fmaxf(g1, g2));
    float e0 = __expf(g0 - gm), e1 = __expf(g1 - gm), e2 = __expf(g2 - gm);
    float ls = __logf(e0 + e1 + e2);
    float lw0 = g0 - gm - ls, lw1 = g1 - gm - ls, lw2 = g2 - gm - ls;

    const int s_local = tid >> 2;       // 0..63
    const int ds      = tid & 3;        // 32-dim slice
    const int s       = s0 + s_local;

    // ---- Q slice -> registers (fp32)
    float q[32];
    {
        const __bf16* qp = qkv + (size_t)(b * S_ + s) * TRI_ + h * HD_ + ds * 32;
        #pragma unroll
        for (int j = 0; j < 4; ++j) {
            bf16x8 qv = *(const bf16x8*)(qp + j * 8);
            #pragma unroll
            for (int k = 0; k < 8; ++k) q[j * 8 + k] = (float)qv[k];
        }
    }

    // anchor LDS slots
    int slot[12];
    const int offs[10] = {-3, -2, -1, 1, 2, 3, -10, -5, 5, 10};
    #pragma unroll
    for (int a = 0; a < 10; ++a) slot[a] = s_local + 10 + offs[a];   // 0..83
    slot[10] = 84; slot[11] = 85;

    __syncthreads();

    const float scale = 0.08838834764831845f;
    float p[12];
    float mx = -1e30f;
    #pragma unroll
    for (int a = 0; a < 12; ++a) {
        const int ro = slot[a] * 128;
        const int sw = slot[a] & 7;
        float d = 0.f;
        #pragma unroll
        for (int j = 0; j < 4; ++j) {
            bf16x8 kv = *(const bf16x8*)&sKV[ro + ((ds * 4 + j) ^ sw) * 8];
            #pragma unroll
            for (int k = 0; k < 8; ++k) d += q[j * 8 + k] * (float)kv[k];
        }
        d += __shfl_xor(d, 1); d += __shfl_xor(d, 2);   // reduce over 4-lane group
        float v = d * scale + (a < 6 ? lw0 : (a < 10 ? lw1 : lw2));
        p[a] = v;
        mx = fmaxf(mx, v);
    }
    float l = 0.f;
    #pragma unroll
    for (int a = 0; a < 12; ++a) { p[a] = __expf(p[a] - mx); l += p[a]; }
    float inv = 1.0f / l;

    float o[32] = {};
    #pragma unroll
    for (int a = 0; a < 12; ++a) {
        const int ro = AROWS * 128 + slot[a] * 128;
        const int sw = slot[a] & 7;
        float pa = p[a];
        #pragma unroll
        for (int j = 0; j < 4; ++j) {
            bf16x8 vv = *(const bf16x8*)&sKV[ro + ((ds * 4 + j) ^ sw) * 8];
            #pragma unroll
            for (int k = 0; k < 8; ++k) o[j * 8 + k] += pa * (float)vv[k];
        }
    }

    __bf16* op = attn_out + (size_t)(b * S_ + s) * DIM_ + h * HD_ + ds * 32;
    #pragma unroll
    for (int j = 0; j < 4; ++j) {
        bf16x8 ov;
        #pragma unroll
        for (int k = 0; k < 8; ++k) ov[k] = (__bf16)(o[j * 8 + k] * inv);
        *(bf16x8*)(op + j * 8) = ov;
    }
}

// ----------------------------------------------------------------------- launcher
extern "C" void kernel_launch(void* const* d_in, const int* in_sizes, int n_in,
                              void* d_out, int out_size, void* d_ws, size_t ws_size,
                              hipStream_t stream) {
    const float* x    = (const float*)d_in[0];
    const float* Wqkv = (const float*)d_in[1];
    const float* bqkv = (const float*)d_in[2];
    const float* Wout = (const float*)d_in[3];
    const float* bout = (const float*)d_in[4];
    const float* gsc  = (const float*)d_in[5];
    float* out = (float*)d_out;

    char* ws = (char*)d_ws;
    __bf16* x_bf   = (__bf16*)(ws);
    __bf16* WqkvT  = (__bf16*)(ws + 12582912);
    __bf16* WoutT  = (__bf16*)(ws + 12582912 + 14155776);
    __bf16* qkv    = (__bf16*)(ws + 12582912 + 14155776 + 4718592);
    __bf16* attn   = (__bf16*)(ws + 12582912 + 14155776 + 4718592 + 37748736);

    // prep: transposes + cvt (one launch)
    {
        int nblk = (TRI_ / 64) * (DIM_ / 64) + (DIM_ / 64) * (DIM_ / 64)
                 + (M_ * DIM_) / 1024;
        prep<<<nblk, 256, 0, stream>>>(Wqkv, WqkvT, Wout, WoutT, x, x_bf);
    }

    // QKV GEMM: 128x192 tiles -> 768 blocks (3.0/CU), single-buffer, NO swizzle
    gemm_qkv<<<(M_ / 128) * (TRI_ / 192), 256, 0, stream>>>(
        x_bf, WqkvT, bqkv, qkv, M_, TRI_, DIM_);

    // anchor attention v2: LDS-tiled, grid (32, 12, 2)
    anchor_attn<<<dim3(32, H_, B_), 256, 0, stream>>>(qkv, gsc, attn);

    // out GEMM: 64x128 tiles, BK=128 single-buffer + XCD swizzle -> 768 blocks
    gemm_out<<<(M_ / 64) * (DIM_ / 128), 256, 0, stream>>>(
        attn, WoutT, bout, out, M_, DIM_, DIM_);
}